// Round 1
// baseline (56.732 us; speedup 1.0000x reference)
//
#include <hip/hip_runtime.h>

#define H 384
#define W 384
#define C 19
#define NB 4
#define HP 382               // H - K + 1
#define HW (H * W)
#define TOTAL_TERMS 47279376.0f   // NB * 81 * HP*HP

// number of kernel-offsets a in [0,2] with 0 <= a+d <= 2 and 0 <= p-a <= HP-1
__device__ __forceinline__ int multv(int p, int d) {
    int lo = max(max(0, -d), p - (HP - 1));
    int hi = min(min(2, 2 - d), p);
    return max(0, hi - lo + 1);
}

__device__ __forceinline__ float bce(float x, float y) {
    // max(x,0) - x*y + log1p(exp(-|x|))
    return fmaxf(x, 0.0f) - x * y + log1pf(__expf(-fabsf(x)));
}

__global__ __launch_bounds__(256) void affinity_partial(
        const float* __restrict__ logits,
        const int* __restrict__ labels,
        float* __restrict__ partial) {
    const int idx = blockIdx.x * 256 + threadIdx.x;   // grid is exact: NB*H*W
    const int n  = idx / HW;
    const int r  = idx % HW;
    const int py = r / W;
    const int px = r % W;

    const float* lp  = logits + (size_t)n * C * HW;
    const int*   lab = labels + (size_t)n * HW;

    float v[C];
#pragma unroll
    for (int c = 0; c < C; ++c) v[c] = lp[c * HW + py * W + px];
    const int myl = lab[py * W + px];

    float acc = 0.0f;

    // d == (0,0): x = ||v||^2, y = 1
    {
        float x = 0.0f;
#pragma unroll
        for (int c = 0; c < C; ++c) x += v[c] * v[c];
        const float w = (float)(multv(py, 0) * multv(px, 0));
        acc += w * bce(x, 1.0f);
    }

    // 12 half-offsets, weight 2 (d and -d give identical terms)
    const int offs_y[12] = {0, 0, 1, 1, 1, 1, 1, 2, 2, 2, 2, 2};
    const int offs_x[12] = {1, 2, -2, -1, 0, 1, 2, -2, -1, 0, 1, 2};
#pragma unroll
    for (int o = 0; o < 12; ++o) {
        const int dy = offs_y[o], dx = offs_x[o];
        const int wgt = multv(py, dy) * multv(px, dx);
        if (wgt > 0) {
            const int qy = py + dy, qx = px + dx;  // in-bounds iff wgt > 0
            float x = 0.0f;
#pragma unroll
            for (int c = 0; c < C; ++c) x += v[c] * lp[c * HW + qy * W + qx];
            const float y = (myl == lab[qy * W + qx]) ? 1.0f : 0.0f;
            acc += 2.0f * (float)wgt * bce(x, y);
        }
    }

    // block reduction: wave shuffle then LDS across the 4 waves
#pragma unroll
    for (int off = 32; off > 0; off >>= 1) acc += __shfl_down(acc, off, 64);
    __shared__ float sm[4];
    const int lane = threadIdx.x & 63, wid = threadIdx.x >> 6;
    if (lane == 0) sm[wid] = acc;
    __syncthreads();
    if (threadIdx.x == 0)
        partial[blockIdx.x] = sm[0] + sm[1] + sm[2] + sm[3];
}

__global__ __launch_bounds__(256) void reduce_final(
        const float* __restrict__ partial, int n, float* __restrict__ out) {
    float s = 0.0f;
    for (int i = threadIdx.x; i < n; i += 256) s += partial[i];
#pragma unroll
    for (int off = 32; off > 0; off >>= 1) s += __shfl_down(s, off, 64);
    __shared__ float sm[4];
    const int lane = threadIdx.x & 63, wid = threadIdx.x >> 6;
    if (lane == 0) sm[wid] = s;
    __syncthreads();
    if (threadIdx.x == 0)
        out[0] = (sm[0] + sm[1] + sm[2] + sm[3]) / TOTAL_TERMS;
}

extern "C" void kernel_launch(void* const* d_in, const int* in_sizes, int n_in,
                              void* d_out, int out_size, void* d_ws, size_t ws_size,
                              hipStream_t stream) {
    const float* logits = (const float*)d_in[0];
    const int*   labels = (const int*)d_in[1];
    float* out     = (float*)d_out;
    float* partial = (float*)d_ws;   // 2304 floats = 9216 B

    const int nthreads = NB * HW;          // 589824
    const int nblocks  = nthreads / 256;   // 2304

    affinity_partial<<<nblocks, 256, 0, stream>>>(logits, labels, partial);
    reduce_final<<<1, 256, 0, stream>>>(partial, nblocks, out);
}

// Round 2
// 37.115 us; speedup vs baseline: 1.5285x; 1.5285x over previous
//
#include <hip/hip_runtime.h>

#define H 384
#define W 384
#define C 19
#define NB 4
#define HP 382               // H - K + 1
#define HW (H * W)
#define CHW (C * HW)
#define TOTAL_TERMS 47279376.0f   // NB * 81 * HP*HP

// number of kernel-offsets a in [0,2] with 0 <= a+d <= 2 and 0 <= p-a <= HP-1
__device__ __forceinline__ int multv(int p, int d) {
    int lo = max(max(0, -d), p - (HP - 1));
    int hi = min(min(2, 2 - d), p);
    return max(0, hi - lo + 1);
}

__device__ __forceinline__ float bce_fast(float x, float y) {
    // max(x,0) - x*y + log1p(exp(-|x|)), fast-math variant
    float t = __expf(-fabsf(x));
    return fmaxf(x, 0.0f) - x * y + __logf(1.0f + t);
}

// Each thread owns 4 consecutive x-pixels. 64 threads/block (1 wave).
// Grid: NB*H*(W/4)/64 = 2304 blocks.
__global__ __launch_bounds__(64) void affinity_partial(
        const float* __restrict__ logits,
        const int* __restrict__ labels,
        float* __restrict__ partial) {
    const int t   = blockIdx.x * 64 + threadIdx.x;   // [0, 147456)
    const int xg  = t % 96;
    const int rs  = t / 96;
    const int py  = rs % H;
    const int n   = rs / H;
    const int px0 = xg * 4;

    // clamped x window: we stage x = x0c .. x0c+11 (12 floats, 3 x float4)
    const int x0c = max(0, px0 - 4);
    const int d1  = px0 - x0c;                 // 0 or 4
    const int d2  = min(W - 4, px0 + 4) - x0c; // 4 or 8
    // clamped row offsets (elements)
    const int ro1 = (min(py + 1, H - 1) - py) * W;
    const int ro2 = (min(py + 2, H - 1) - py) * W;

    const float* p0 = logits + (size_t)n * CHW + (size_t)py * W + x0c;

    float acc[4][13];
#pragma unroll
    for (int i = 0; i < 4; ++i)
#pragma unroll
        for (int o = 0; o < 13; ++o) acc[i][o] = 0.0f;

    for (int c = 0; c < C; ++c) {
        const float* pr = p0 + (size_t)c * HW;
        float a[12], b[12], e[12];
        *(float4*)&a[0] = *(const float4*)(pr);
        *(float4*)&a[4] = *(const float4*)(pr + d1);
        *(float4*)&a[8] = *(const float4*)(pr + d2);
        *(float4*)&b[0] = *(const float4*)(pr + ro1);
        *(float4*)&b[4] = *(const float4*)(pr + ro1 + d1);
        *(float4*)&b[8] = *(const float4*)(pr + ro1 + d2);
        *(float4*)&e[0] = *(const float4*)(pr + ro2);
        *(float4*)&e[4] = *(const float4*)(pr + ro2 + d1);
        *(float4*)&e[8] = *(const float4*)(pr + ro2 + d2);

#pragma unroll
        for (int i = 0; i < 4; ++i) {
            const float s = a[4 + i];
            acc[i][0] += s * s;             // (dy,dx)=(0,0)
            acc[i][1] += s * a[5 + i];      // (0,1)
            acc[i][2] += s * a[6 + i];      // (0,2)
#pragma unroll
            for (int dx = 0; dx < 5; ++dx) {
                acc[i][3 + dx] += s * b[2 + i + dx];   // (1, dx-2)
                acc[i][8 + dx] += s * e[2 + i + dx];   // (2, dx-2)
            }
        }
    }

    // labels (same staging scheme; clamped rows/cols only feed weight-0 terms)
    const int* lb = labels + (size_t)n * HW + (size_t)py * W + x0c;
    int la[12], lbr[12], ler[12];
    *(int4*)&la[0]  = *(const int4*)(lb);
    *(int4*)&la[4]  = *(const int4*)(lb + d1);
    *(int4*)&la[8]  = *(const int4*)(lb + d2);
    *(int4*)&lbr[0] = *(const int4*)(lb + ro1);
    *(int4*)&lbr[4] = *(const int4*)(lb + ro1 + d1);
    *(int4*)&lbr[8] = *(const int4*)(lb + ro1 + d2);
    *(int4*)&ler[0] = *(const int4*)(lb + ro2);
    *(int4*)&ler[4] = *(const int4*)(lb + ro2 + d1);
    *(int4*)&ler[8] = *(const int4*)(lb + ro2 + d2);

    const int wy0 = multv(py, 0);
    const int wy1 = multv(py, 1);
    const int wy2 = multv(py, 2);

    float total = 0.0f;
#pragma unroll
    for (int i = 0; i < 4; ++i) {
        const int px = px0 + i;
        int wx[5];
#pragma unroll
        for (int dxi = 0; dxi < 5; ++dxi) wx[dxi] = multv(px, dxi - 2);
        const int ls = la[4 + i];

        // (0,0): y = 1, not doubled
        total += (float)(wy0 * wx[2]) * bce_fast(acc[i][0], 1.0f);
        // (0,1), (0,2): doubled (symmetry with (0,-1),(0,-2))
        total += 2.0f * (float)(wy0 * wx[3]) *
                 bce_fast(acc[i][1], (ls == la[5 + i]) ? 1.0f : 0.0f);
        total += 2.0f * (float)(wy0 * wx[4]) *
                 bce_fast(acc[i][2], (ls == la[6 + i]) ? 1.0f : 0.0f);
#pragma unroll
        for (int dxi = 0; dxi < 5; ++dxi) {
            total += 2.0f * (float)(wy1 * wx[dxi]) *
                     bce_fast(acc[i][3 + dxi], (ls == lbr[2 + i + dxi]) ? 1.0f : 0.0f);
            total += 2.0f * (float)(wy2 * wx[dxi]) *
                     bce_fast(acc[i][8 + dxi], (ls == ler[2 + i + dxi]) ? 1.0f : 0.0f);
        }
    }

    // single-wave block: shuffle reduce, lane 0 writes
#pragma unroll
    for (int off = 32; off > 0; off >>= 1) total += __shfl_down(total, off, 64);
    if (threadIdx.x == 0) partial[blockIdx.x] = total;
}

__global__ __launch_bounds__(256) void reduce_final(
        const float* __restrict__ partial, int n, float* __restrict__ out) {
    float s = 0.0f;
    for (int i = threadIdx.x; i < n; i += 256) s += partial[i];
#pragma unroll
    for (int off = 32; off > 0; off >>= 1) s += __shfl_down(s, off, 64);
    __shared__ float sm[4];
    const int lane = threadIdx.x & 63, wid = threadIdx.x >> 6;
    if (lane == 0) sm[wid] = s;
    __syncthreads();
    if (threadIdx.x == 0)
        out[0] = (sm[0] + sm[1] + sm[2] + sm[3]) / TOTAL_TERMS;
}

extern "C" void kernel_launch(void* const* d_in, const int* in_sizes, int n_in,
                              void* d_out, int out_size, void* d_ws, size_t ws_size,
                              hipStream_t stream) {
    const float* logits = (const float*)d_in[0];
    const int*   labels = (const int*)d_in[1];
    float* out     = (float*)d_out;
    float* partial = (float*)d_ws;   // 2304 floats

    const int nthreads = NB * H * (W / 4);   // 147456
    const int nblocks  = nthreads / 64;      // 2304

    affinity_partial<<<nblocks, 64, 0, stream>>>(logits, labels, partial);
    reduce_final<<<1, 256, 0, stream>>>(partial, nblocks, out);
}